// Round 14
// baseline (218.388 us; speedup 1.0000x reference)
//
#include <hip/hip_runtime.h>
#include <hip/hip_cooperative_groups.h>

#define BB 4
#define NN 4096
#define DD 64
#define KK 16
#define NBUCK 2048
#define NCHB 144              // boundary chunks per batch (4-tile chunks)
#define NBND (NCHB * BB)      // 576
#define NLOV 64               // lovasz point-major units
#define NUNIT (NLOV + NBND)   // 640 work units in phase 3
#define CGRID 256             // cooperative grid (1 block/CU -- conservative)

// ws float offsets (ws_size = 256 MiB, plenty)
#define OFF_EMB   0u          // B*N*D fp32 normalized emb
#define OFF_NRM2  1048576u    // B*N
#define OFF_PFC   1064960u    // 256*K*D partials
#define OFF_PGC   1327104u    // 256*K*3
#define OFF_PCNT  1339392u    // 256*K
#define OFF_FC    1343488u    // B*K*D
#define OFF_CEN   1347584u    // B*K*D
#define OFF_GC    1351680u    // B*K*3
#define OFF_FCN   1351872u    // B*K
#define OFF_FCN2  1351936u
#define OFF_CEN2  1352000u
#define OFF_GC2   1352064u
#define OFF_CNTF  1352128u
#define OFF_BND   1352192u    // 576
#define OFF_VAR   1352768u    // 64
#define OFF_CENL  1352832u    // 64
#define OFF_LOV   1352896u    // 64
#define OFF_PH    1353216u    // 64 bk * 4096 (u32 hist[2048] + f32 ssum[2048])
#define OFF_EMBH  1615360u    // bf16 normalized emb (524288 float slots)

typedef __attribute__((ext_vector_type(8))) short bf16x8;
typedef __attribute__((ext_vector_type(4))) float f32x4;

#define FSQRT(x) __builtin_amdgcn_sqrtf(x)
#define FRCP(x)  __builtin_amdgcn_rcpf(x)
#define FRSQ(x)  __builtin_amdgcn_rsqf(x)

__device__ __forceinline__ ushort f2bf(float x){
  unsigned u = __float_as_uint(x);
  return (ushort)((u + 0x7FFFu + ((u >> 16) & 1u)) >> 16);
}

__device__ __forceinline__ float blockReduceSum(float v, float* sbuf){
  int t = threadIdx.x;
  #pragma unroll
  for (int off = 32; off > 0; off >>= 1) v += __shfl_xor(v, off, 64);
  if ((t & 63) == 0) sbuf[t >> 6] = v;
  __syncthreads();
  float s = 0.f;
  if (t == 0){
    int nw = blockDim.x >> 6;
    for (int i = 0; i < nw; i++) s += sbuf[i];
  }
  __syncthreads();
  return s;
}

__device__ __forceinline__ double blockReduceD(double v, double* sbuf){
  int t = threadIdx.x;
  #pragma unroll
  for (int off = 32; off > 0; off >>= 1) v += __shfl_xor(v, off, 64);
  if ((t & 63) == 0) sbuf[t >> 6] = v;
  __syncthreads();
  double s = 0.0;
  if (t == 0){
    for (int i = 0; i < 4; i++) s += sbuf[i];
  }
  __syncthreads();
  return s;
}

// ===================== phase bodies (shared by both paths) =====================

__device__ void phase_norm(int blk, const float* __restrict__ emb,
                           const float* __restrict__ pts, const int* __restrict__ lbl,
                           float* __restrict__ ws,
                           float* fcl, float* gclS, float* cntl){
  int t = threadIdx.x;
  for (int i = t; i < KK * DD; i += 256) fcl[i] = 0.f;
  if (t < KK * 3) gclS[t] = 0.f;
  if (t < KK) cntl[t] = 0.f;
  __syncthreads();

  int lane = t & 63, w = t >> 6;
  int b = blk >> 6;
  int local = blk & 63;
  int base = local * 64 + w * 16;
  const float* E = emb + (size_t)b * NN * DD;
  float* EN = ws + OFF_EMB + (size_t)b * NN * DD;
  ushort* EH = (ushort*)(ws + OFF_EMBH) + (size_t)b * NN * DD;

  for (int i = 0; i < 16; i++){
    int n = base + i;
    float v = E[(size_t)n * DD + lane];
    float ss = v * v;
    #pragma unroll
    for (int off = 1; off < 64; off <<= 1) ss += __shfl_xor(ss, off, 64);
    float nrm = FSQRT(ss);
    float scale = FRCP(fmaxf(nrm, 1e-12f));
    float vn = v * scale;
    EN[(size_t)n * DD + lane] = vn;
    EH[(size_t)n * DD + lane] = f2bf(vn);
    if (lane == 0) ws[OFF_NRM2 + b * NN + n] = ss * scale * scale;
    int l = lbl[b * NN + n];
    if (l >= 1 && l <= KK){
      int k = l - 1;
      atomicAdd(&fcl[k * DD + lane], vn);
      if (lane < 3) atomicAdd(&gclS[k * 3 + lane], pts[((size_t)b * NN + n) * 3 + lane]);
      if (lane == 0) atomicAdd(&cntl[k], 1.0f);
    }
  }
  __syncthreads();
  for (int i = t; i < KK * DD; i += 256)
    ws[OFF_PFC + (size_t)blk * KK * DD + i] = fcl[i];
  if (t < KK * 3) ws[OFF_PGC + blk * KK * 3 + t] = gclS[t];
  if (t < KK)     ws[OFF_PCNT + blk * KK + t] = cntl[t];
}

__device__ void phase_centers(int bk, float* __restrict__ ws, float (*accL)[DD]){
  int b = bk >> 4, k = bk & 15;
  int t = threadIdx.x;
  int lane = t & 63, w = t >> 6;
  float s = 0.f;
  #pragma unroll
  for (int j = 0; j < 16; j++)
    s += ws[OFF_PFC + (size_t)((b * 64 + w * 16 + j) * KK + k) * DD + lane];
  accL[w][lane] = s;
  __syncthreads();
  for (int i = t; i < 4096; i += 256) ws[OFF_PH + bk * 4096 + i] = 0.f;
  if (w == 0){
    float fsum = accL[0][lane] + accL[1][lane] + accL[2][lane] + accL[3][lane];
    float cp  = ws[OFF_PCNT + (b * 64 + lane) * KK + k];
    float gp0 = ws[OFF_PGC + ((b * 64 + lane) * KK + k) * 3 + 0];
    float gp1 = ws[OFF_PGC + ((b * 64 + lane) * KK + k) * 3 + 1];
    float gp2 = ws[OFF_PGC + ((b * 64 + lane) * KK + k) * 3 + 2];
    #pragma unroll
    for (int off = 1; off < 64; off <<= 1){
      cp  += __shfl_xor(cp, off, 64);
      gp0 += __shfl_xor(gp0, off, 64);
      gp1 += __shfl_xor(gp1, off, 64);
      gp2 += __shfl_xor(gp2, off, 64);
    }
    float inv_c = FRCP(cp);
    float f = fsum * inv_c;
    ws[OFF_FC + (size_t)(b * KK + k) * DD + lane] = f;
    float n2 = f * f;
    #pragma unroll
    for (int off = 1; off < 64; off <<= 1) n2 += __shfl_xor(n2, off, 64);
    float fn = FSQRT(n2);
    float inv = FRCP(fmaxf(fn, 1e-12f));
    float ce = f * inv;
    ws[OFF_CEN + (size_t)(b * KK + k) * DD + lane] = ce;
    float g0 = gp0 * inv_c, g1 = gp1 * inv_c, g2 = gp2 * inv_c;
    if (lane == 0){
      ws[OFF_GC + (b * KK + k) * 3 + 0] = g0;
      ws[OFF_GC + (b * KK + k) * 3 + 1] = g1;
      ws[OFF_GC + (b * KK + k) * 3 + 2] = g2;
      ws[OFF_FCN  + b * KK + k] = fn;
      ws[OFF_FCN2 + b * KK + k] = n2;
      ws[OFF_CEN2 + b * KK + k] = n2 * inv * inv;
      ws[OFF_GC2  + b * KK + k] = g0 * g0 + g1 * g1 + g2 * g2;
      ws[OFF_CNTF + b * KK + k] = cp;
    }
  }
}

__device__ void phase_lovasz1(int blk, const int* __restrict__ lbl,
                              const float* __restrict__ pts, float* __restrict__ ws,
                              float* red, float* invmfnS, float* invfcS, float* invCS,
                              float* fcn2S, float* cen2S, float* gc2S, float (*gcS)[3]){
  int t = threadIdx.x;
  int g = blk * 256 + t;
  int b = g >> 12;
  int n = g & (NN - 1);
  if (t < KK){
    float fcn = ws[OFF_FCN + b * KK + t];
    invmfnS[t] = FRCP(fmaxf(fcn, 1e-8f));
    invfcS[t]  = FRCP(fmaxf(fcn, 1e-12f));
    invCS[t]   = FRCP(ws[OFF_CNTF + b * KK + t]);
    fcn2S[t]   = ws[OFF_FCN2 + b * KK + t];
    cen2S[t]   = ws[OFF_CEN2 + b * KK + t];
    gc2S[t]    = ws[OFF_GC2  + b * KK + t];
    gcS[t][0]  = ws[OFF_GC + (b * KK + t) * 3 + 0];
    gcS[t][1]  = ws[OFF_GC + (b * KK + t) * 3 + 1];
    gcS[t][2]  = ws[OFF_GC + (b * KK + t) * 3 + 2];
  }
  __syncthreads();

  const float* EN = ws + OFF_EMB + (size_t)(b * NN + n) * DD;
  float4 e4[16];
  #pragma unroll
  for (int i = 0; i < 16; i++) e4[i] = *(const float4*)&EN[i * 4];
  float nrm2 = ws[OFF_NRM2 + b * NN + n];
  float rs = FRSQ(nrm2);
  int l = lbl[b * NN + n];
  float p0 = pts[((size_t)b * NN + n) * 3 + 0];
  float p1 = pts[((size_t)b * NN + n) * 3 + 1];
  float p2 = pts[((size_t)b * NN + n) * 3 + 2];
  float p2sum = p0 * p0 + p1 * p1 + p2 * p2;
  float varA = 0.f, cenA = 0.f;

  for (int k = 0; k < KK; k++){
    const float* FCk = ws + OFF_FC + (size_t)(b * KK + k) * DD;
    float dx = 0.f, dy = 0.f, dz = 0.f, dw = 0.f;
    #pragma unroll
    for (int i = 0; i < 16; i++){
      float4 f = *(const float4*)&FCk[i * 4];
      dx += e4[i].x * f.x; dy += e4[i].y * f.y;
      dz += e4[i].z * f.z; dw += e4[i].w * f.w;
    }
    float dot = (dx + dy) + (dz + dw);
    float sim = dot * rs * invmfnS[k];
    int m = (l == k + 1) ? 1 : 0;
    if (sim > 0.f){
      int q = (int)(sim * (float)NBUCK);
      q = q > NBUCK - 1 ? NBUCK - 1 : q;
      int qi = NBUCK - 1 - q;
      unsigned* H = (unsigned*)(ws + OFF_PH) + (size_t)(b * KK + k) * 4096;
      float* S = ws + OFF_PH + (size_t)(b * KK + k) * 4096 + 2048;
      atomicAdd(&H[qi], 1u + ((unsigned)m << 16));
      atomicAdd(&S[qi], sim);
    }
    if (m){
      float dotc = dot * invfcS[k];
      float dnc = FSQRT(fmaxf(nrm2 + cen2S[k] - 2.f * dotc, 0.f));
      varA += fmaxf(dnc - 0.5f, 0.f) * invCS[k];
      float fd = FSQRT(fmaxf(nrm2 + fcn2S[k] - 2.f * dot, 0.f));
      float sd2 = p2sum + gc2S[k] - 2.f * (p0 * gcS[k][0] + p1 * gcS[k][1] + p2 * gcS[k][2]);
      cenA += FSQRT(fmaxf(sd2, 0.f)) * fd * invCS[k];
    }
  }
  float vs = blockReduceSum(varA, red);
  if (t == 0) ws[OFF_VAR + blk] = vs;
  float cs = blockReduceSum(cenA, red);
  if (t == 0) ws[OFF_CENL + blk] = cs;
}

__device__ void phase_boundary(int q, const int* __restrict__ lbl,
                               const ushort* __restrict__ EHg,
                               float* __restrict__ ws, float* red){
  int t = threadIdx.x;
  int b = q / NCHB;
  int cq = q - b * NCHB;
  int ti = 0, rem = cq;
  while (rem >= ((32 - ti + 3) >> 2)){ rem -= (32 - ti + 3) >> 2; ti++; }
  int tj0 = ti + rem * 4;
  int nt = 32 - tj0; if (nt > 4) nt = 4;

  int lane = t & 63, w = t >> 6;
  int lm = lane & 15;
  int rif = (lane >> 4) * 4;
  int lk = (lane >> 4) * 8;
  const ushort* E = EHg + (size_t)b * NN * DD;
  const float* NR = ws + OFF_NRM2 + b * NN;
  const int* LB = lbl + b * NN;

  bf16x8 a[2][2];
  #pragma unroll
  for (int rb = 0; rb < 2; rb++)
    #pragma unroll
    for (int kh = 0; kh < 2; kh++)
      a[rb][kh] = *(const bf16x8*)&E[(size_t)(ti * 128 + w * 32 + rb * 16 + lm) * DD + kh * 32 + lk];

  float nAr[8]; int lAr[8];
  #pragma unroll
  for (int rb = 0; rb < 2; rb++)
    #pragma unroll
    for (int r = 0; r < 4; r++){
      int gi = ti * 128 + w * 32 + rb * 16 + rif + r;
      nAr[rb * 4 + r] = NR[gi];
      lAr[rb * 4 + r] = LB[gi];
    }

  float sum = 0.f;
  for (int tt = 0; tt < nt; tt++){
    int tj = tj0 + tt;
    bool diag = (tj == ti);
    #pragma unroll
    for (int pass = 0; pass < 2; pass++){
      float nBr[4]; int lBr[4];
      #pragma unroll
      for (int cb = 0; cb < 4; cb++){
        int gj = tj * 128 + (pass * 4 + cb) * 16 + lm;
        nBr[cb] = NR[gj];
        lBr[cb] = LB[gj];
      }
      f32x4 ac[2][4];
      #pragma unroll
      for (int rb = 0; rb < 2; rb++)
        #pragma unroll
        for (int cb = 0; cb < 4; cb++) ac[rb][cb] = (f32x4){0.f, 0.f, 0.f, 0.f};
      #pragma unroll
      for (int cb = 0; cb < 4; cb++){
        #pragma unroll
        for (int kh = 0; kh < 2; kh++){
          bf16x8 bb = *(const bf16x8*)&E[(size_t)(tj * 128 + (pass * 4 + cb) * 16 + lm) * DD + kh * 32 + lk];
          ac[0][cb] = __builtin_amdgcn_mfma_f32_16x16x32_bf16(a[0][kh], bb, ac[0][cb], 0, 0, 0);
          ac[1][cb] = __builtin_amdgcn_mfma_f32_16x16x32_bf16(a[1][kh], bb, ac[1][cb], 0, 0, 0);
        }
      }
      if (diag){
        #pragma unroll
        for (int rb = 0; rb < 2; rb++)
          #pragma unroll
          for (int cb = 0; cb < 4; cb++)
            #pragma unroll
            for (int r = 0; r < 4; r++){
              float d2 = fmaxf(nAr[rb * 4 + r] + nBr[cb] - 2.f * ac[rb][cb][r], 0.f);
              if (lAr[rb * 4 + r] == lBr[cb]) d2 = 0.f;
              float f = fmaxf(1.5f - FSQRT(d2), 0.f);
              int gi = w * 32 + rb * 16 + rif + r;
              int gj = (pass * 4 + cb) * 16 + lm;
              sum += (gi < gj) ? f : 0.f;
            }
      } else {
        #pragma unroll
        for (int rb = 0; rb < 2; rb++)
          #pragma unroll
          for (int cb = 0; cb < 4; cb++)
            #pragma unroll
            for (int r = 0; r < 4; r++){
              float d2 = fmaxf(nAr[rb * 4 + r] + nBr[cb] - 2.f * ac[rb][cb][r], 0.f);
              if (lAr[rb * 4 + r] == lBr[cb]) d2 = 0.f;
              sum += fmaxf(1.5f - FSQRT(d2), 0.f);
            }
      }
    }
  }
  float s = blockReduceSum(sum, red);
  if (t == 0) ws[OFF_BND + q] = s;
}

__device__ void phase_lov2(int bk, float* __restrict__ ws, float* red, unsigned* wsumS){
  int b = bk >> 4, k = bk & 15;
  int t = threadIdx.x;
  int lane = t & 63, w = t >> 6;
  const unsigned* H = (const unsigned*)(ws + OFF_PH) + (size_t)bk * 4096;
  const float* S = ws + OFF_PH + (size_t)bk * 4096 + 2048;
  float C = ws[OFF_CNTF + b * KK + k];

  int base = t * 8;
  unsigned hv[8]; float sv[8];
  #pragma unroll
  for (int i = 0; i < 8; i++){ hv[i] = H[base + i]; sv[i] = S[base + i]; }
  unsigned loc[8];
  unsigned run = 0;
  #pragma unroll
  for (int i = 0; i < 8; i++){ loc[i] = run; run += hv[i]; }
  unsigned tot = run, sc = tot;
  #pragma unroll
  for (int off = 1; off < 64; off <<= 1){
    unsigned v = __shfl_up(sc, off, 64);
    if (lane >= off) sc += v;
  }
  if (lane == 63) wsumS[w] = sc;
  __syncthreads();
  unsigned wbase = 0;
  #pragma unroll
  for (int w2 = 0; w2 < 4; w2++) if (w2 < w) wbase += wsumS[w2];
  unsigned ex = wbase + sc - tot;

  float contrib = 0.f;
  #pragma unroll
  for (int i = 0; i < 8; i++){
    unsigned h = hv[i];
    unsigned g = h & 0xFFFFu, mu = h >> 16;
    if (g){
      unsigned pre = ex + loc[i];
      float i0 = (float)(pre & 0xFFFFu), c0 = (float)(pre >> 16);
      float i1 = i0 + (float)g, c1 = c0 + (float)mu;
      float jac0 = 1.f - (C - c0) * FRCP(C + i0 - c0);
      float jac1 = 1.f - (C - c1) * FRCP(C + i1 - c1);
      contrib += sv[i] * (jac1 - jac0) * FRCP((float)g);
    }
  }
  float ls = blockReduceSum(contrib, red);
  if (t == 0) ws[OFF_LOV + bk] = ls;
}

__device__ void phase_final(const float* __restrict__ ws, float* __restrict__ out,
                            float* red, double* dred){
  int t = threadIdx.x;
  double bs = 0.0;
  for (int i = t; i < NBND; i += 256) bs += (double)ws[OFF_BND + i];
  bs = blockReduceD(bs, dred);
  double lv = (t < 64) ? (double)ws[OFF_LOV + t] : 0.0;
  lv = blockReduceD(lv, dred);
  double va = (t < 64) ? (double)ws[OFF_VAR + t] : 0.0;
  va = blockReduceD(va, dred);
  double ce = (t < 64) ? (double)ws[OFF_CENL + t] : 0.0;
  ce = blockReduceD(ce, dred);

  double di = 0.0, rg = 0.0;
  int i = t >> 4, j = t & 15;
  for (int b = 0; b < BB; b++){
    float v = 0.f;
    if (i != j){
      float dot = 0.f;
      #pragma unroll
      for (int d = 0; d < DD; d++)
        dot += ws[OFF_CEN + (size_t)(b * KK + i) * DD + d] * ws[OFF_CEN + (size_t)(b * KK + j) * DD + d];
      float cd = FSQRT(fmaxf(ws[OFF_CEN2 + b * KK + i] + ws[OFF_CEN2 + b * KK + j] - 2.f * dot, 0.f));
      v = fmaxf(3.f - cd, 0.f);
    }
    float s = blockReduceSum(v, red);
    if (t == 0){
      di += (double)(s / 240.f);
      float s2 = 0.f;
      for (int k = 0; k < KK; k++) s2 += ws[OFF_CEN2 + b * KK + k];
      rg += (double)(FSQRT(s2) * 0.001f);
    }
  }
  if (t == 0){
    double var_l  = va / (4.0 + 1e-6);
    double dist_l = di / (4.0 + 1e-6);
    double reg_l  = rg / (4.0 + 1e-6);
    double cen_l  = ce / 4.0;
    double bnd_l  = (2.0 * bs + 1.5 * (double)NN * BB) / ((double)NN * NN * BB);
    double lov_l  = lv / 4.0;
    double total = 0.1 * (var_l + dist_l + reg_l) + 0.1 * cen_l + 0.05 * bnd_l + 0.01 * lov_l;
    out[0] = (float)total; out[1] = (float)var_l; out[2] = (float)dist_l;
    out[3] = (float)reg_l; out[4] = (float)cen_l; out[5] = (float)bnd_l;
    out[6] = (float)lov_l;
  }
}

// ===================== fallback multi-kernel path (R11) =====================

__global__ void knormacc(const float* __restrict__ emb, const float* __restrict__ pts,
                         const int* __restrict__ lbl, float* __restrict__ ws){
  __shared__ float fcl[KK * DD];
  __shared__ float gclS[KK * 3];
  __shared__ float cntl[KK];
  phase_norm(blockIdx.x, emb, pts, lbl, ws, fcl, gclS, cntl);
}

__global__ void kcenters(float* __restrict__ ws){
  __shared__ float accL[4][DD];
  phase_centers(blockIdx.x, ws, accL);
}

__global__ __launch_bounds__(256, 4) void kfused(const int* __restrict__ lbl,
                                                 const ushort* __restrict__ EHg,
                                                 const float* __restrict__ pts,
                                                 float* __restrict__ ws){
  __shared__ float red[16];
  if (blockIdx.x < NLOV){
    __shared__ float invmfnS[KK], invfcS[KK], invCS[KK], fcn2S[KK], cen2S[KK], gc2S[KK];
    __shared__ float gcS[KK][3];
    phase_lovasz1(blockIdx.x, lbl, pts, ws, red, invmfnS, invfcS, invCS,
                  fcn2S, cen2S, gc2S, gcS);
  } else {
    phase_boundary(blockIdx.x - NLOV, lbl, EHg, ws, red);
  }
}

__global__ void klov2(float* __restrict__ ws){
  __shared__ unsigned wsumS[4];
  __shared__ float red[16];
  phase_lov2(blockIdx.x, ws, red, wsumS);
}

__global__ void kfinal(const float* __restrict__ ws, float* __restrict__ out){
  __shared__ double dred[4];
  __shared__ float red[16];
  phase_final(ws, out, red, dred);
}

// ===================== cooperative single-kernel path =====================

__global__ __launch_bounds__(256, 4) void kall(const float* __restrict__ pts,
                                               const float* __restrict__ emb,
                                               const int* __restrict__ lbl,
                                               float* __restrict__ ws,
                                               float* __restrict__ out){
  cooperative_groups::grid_group grid = cooperative_groups::this_grid();
  __shared__ float fcl[KK * DD];       // P1 (aliases: also covers P2's accL needs)
  __shared__ float gclS[KK * 3];
  __shared__ float cntl[KK];
  __shared__ float accL[4][DD];
  __shared__ float red[16];
  __shared__ double dred[4];
  __shared__ float invmfnS[KK], invfcS[KK], invCS[KK], fcn2S[KK], cen2S[KK], gc2S[KK];
  __shared__ float gcS[KK][3];
  __shared__ unsigned wsumS[4];

  // P1: normalize + partials (all 256 blocks)
  phase_norm(blockIdx.x, emb, pts, lbl, ws, fcl, gclS, cntl);
  grid.sync();

  // P2: centers finalize + PH zero (blocks 0..63)
  if (blockIdx.x < 64) phase_centers(blockIdx.x, ws, accL);
  grid.sync();

  // P3: 640 units over 256 blocks (static partition)
  const ushort* EHg = (const ushort*)(ws + OFF_EMBH);
  for (int unit = blockIdx.x; unit < NUNIT; unit += CGRID){
    if (unit < NLOV)
      phase_lovasz1(unit, lbl, pts, ws, red, invmfnS, invfcS, invCS,
                    fcn2S, cen2S, gc2S, gcS);
    else
      phase_boundary(unit - NLOV, lbl, EHg, ws, red);
    __syncthreads();
  }
  grid.sync();

  // P4: lovasz histogram scan (blocks 0..63)
  if (blockIdx.x < 64) phase_lov2(blockIdx.x, ws, red, wsumS);
  grid.sync();

  // P5: final combine (block 0)
  if (blockIdx.x == 0) phase_final(ws, out, red, dred);
}

extern "C" void kernel_launch(void* const* d_in, const int* in_sizes, int n_in,
                              void* d_out, int out_size, void* d_ws, size_t ws_size,
                              hipStream_t stream){
  const float* pts = (const float*)d_in[0];
  const float* emb = (const float*)d_in[1];
  const int* lbl   = (const int*)d_in[2];
  float* out = (float*)d_out;
  float* ws = (float*)d_ws;

  void* args[] = { (void*)&pts, (void*)&emb, (void*)&lbl, (void*)&ws, (void*)&out };
  hipError_t err = hipLaunchCooperativeKernel((const void*)kall, dim3(CGRID), dim3(256),
                                              args, 0, stream);
  if (err != hipSuccess){
    (void)hipGetLastError();   // clear sticky error; fall back to 5-dispatch path
    hipLaunchKernelGGL(knormacc, dim3(256), dim3(256), 0, stream, emb, pts, lbl, ws);
    hipLaunchKernelGGL(kcenters, dim3(64),  dim3(256), 0, stream, ws);
    hipLaunchKernelGGL(kfused,   dim3(NLOV + NBND), dim3(256), 0, stream,
                       lbl, (const ushort*)(ws + OFF_EMBH), pts, ws);
    hipLaunchKernelGGL(klov2,    dim3(64),  dim3(256), 0, stream, ws);
    hipLaunchKernelGGL(kfinal,   dim3(1),   dim3(256), 0, stream, ws, out);
  }
}

// Round 15
// 77.216 us; speedup vs baseline: 2.8283x; 2.8283x over previous
//
#include <hip/hip_runtime.h>

#define BB 4
#define NN 4096
#define DD 64
#define KK 16
#define NBUCK 2048
#define NCHB 144              // boundary chunks per batch (4-tile chunks)
#define NBND (NCHB * BB)      // 576
#define NLOV 64               // lovasz point-major blocks (1 thread/point)

// ws float offsets (ws_size = 256 MiB, plenty)
#define OFF_EMB   0u          // B*N*D fp32 normalized emb
#define OFF_NRM2  1048576u    // B*N
#define OFF_PFC   1064960u    // 256*K*D partials
#define OFF_PGC   1327104u    // 256*K*3
#define OFF_PCNT  1339392u    // 256*K
#define OFF_FC    1343488u    // B*K*D
#define OFF_CEN   1347584u    // B*K*D
#define OFF_GC    1351680u    // B*K*3
#define OFF_FCN   1351872u    // B*K
#define OFF_FCN2  1351936u
#define OFF_CEN2  1352000u
#define OFF_GC2   1352064u
#define OFF_CNTF  1352128u
#define OFF_BND   1352192u    // 576
#define OFF_VAR   1352768u    // 64
#define OFF_CENL  1352832u    // 64
#define OFF_LOV   1352896u    // 64
#define OFF_PH    1353216u    // 64 bk * 4096 (u32 hist[2048] + f32 ssum[2048])
#define OFF_EMBH  1615360u    // bf16 normalized emb (524288 float slots)

typedef __attribute__((ext_vector_type(8))) short bf16x8;
typedef __attribute__((ext_vector_type(4))) float f32x4;

#define FSQRT(x) __builtin_amdgcn_sqrtf(x)
#define FRCP(x)  __builtin_amdgcn_rcpf(x)
#define FRSQ(x)  __builtin_amdgcn_rsqf(x)

__device__ __forceinline__ ushort f2bf(float x){
  unsigned u = __float_as_uint(x);
  return (ushort)((u + 0x7FFFu + ((u >> 16) & 1u)) >> 16);
}

__device__ __forceinline__ float blockReduceSum(float v, float* sbuf){
  int t = threadIdx.x;
  #pragma unroll
  for (int off = 32; off > 0; off >>= 1) v += __shfl_xor(v, off, 64);
  if ((t & 63) == 0) sbuf[t >> 6] = v;
  __syncthreads();
  float s = 0.f;
  if (t == 0){
    int nw = blockDim.x >> 6;
    for (int i = 0; i < nw; i++) s += sbuf[i];
  }
  __syncthreads();
  return s;
}

__device__ __forceinline__ double blockReduceD(double v, double* sbuf){
  int t = threadIdx.x;
  #pragma unroll
  for (int off = 32; off > 0; off >>= 1) v += __shfl_xor(v, off, 64);
  if ((t & 63) == 0) sbuf[t >> 6] = v;
  __syncthreads();
  double s = 0.0;
  if (t == 0){
    for (int i = 0; i < 4; i++) s += sbuf[i];
  }
  __syncthreads();
  return s;
}

// Normalize embeddings, per-instance partial sums -> private scratch.
__global__ void knormacc(const float* __restrict__ emb, const float* __restrict__ pts,
                         const int* __restrict__ lbl, float* __restrict__ ws){
  __shared__ float fcl[KK * DD];
  __shared__ float gcl[KK * 3];
  __shared__ float cntl[KK];
  int t = threadIdx.x;
  for (int i = t; i < KK * DD; i += 256) fcl[i] = 0.f;
  if (t < KK * 3) gcl[t] = 0.f;
  if (t < KK) cntl[t] = 0.f;
  __syncthreads();

  int lane = t & 63, w = t >> 6;
  int b = blockIdx.x >> 6;
  int local = blockIdx.x & 63;
  int base = local * 64 + w * 16;
  const float* E = emb + (size_t)b * NN * DD;
  float* EN = ws + OFF_EMB + (size_t)b * NN * DD;
  ushort* EH = (ushort*)(ws + OFF_EMBH) + (size_t)b * NN * DD;

  for (int i = 0; i < 16; i++){
    int n = base + i;
    float v = E[(size_t)n * DD + lane];
    float ss = v * v;
    #pragma unroll
    for (int off = 1; off < 64; off <<= 1) ss += __shfl_xor(ss, off, 64);
    float nrm = FSQRT(ss);
    float scale = FRCP(fmaxf(nrm, 1e-12f));
    float vn = v * scale;
    EN[(size_t)n * DD + lane] = vn;
    EH[(size_t)n * DD + lane] = f2bf(vn);
    if (lane == 0) ws[OFF_NRM2 + b * NN + n] = ss * scale * scale;
    int l = lbl[b * NN + n];
    if (l >= 1 && l <= KK){
      int k = l - 1;
      atomicAdd(&fcl[k * DD + lane], vn);
      if (lane < 3) atomicAdd(&gcl[k * 3 + lane], pts[((size_t)b * NN + n) * 3 + lane]);
      if (lane == 0) atomicAdd(&cntl[k], 1.0f);
    }
  }
  __syncthreads();
  for (int i = t; i < KK * DD; i += 256)
    ws[OFF_PFC + (size_t)blockIdx.x * KK * DD + i] = fcl[i];
  if (t < KK * 3) ws[OFF_PGC + blockIdx.x * KK * 3 + t] = gcl[t];
  if (t < KK)     ws[OFF_PCNT + blockIdx.x * KK + t] = cntl[t];
}

// One block per (b,k): reduce partials, finalize centers; zero this bk's PH slice.
__global__ void kcenters(float* __restrict__ ws){
  __shared__ float accL[4][DD];
  int bk = blockIdx.x;
  int b = bk >> 4, k = bk & 15;
  int t = threadIdx.x;
  int lane = t & 63, w = t >> 6;
  float s = 0.f;
  #pragma unroll
  for (int j = 0; j < 16; j++)
    s += ws[OFF_PFC + (size_t)((b * 64 + w * 16 + j) * KK + k) * DD + lane];
  accL[w][lane] = s;
  __syncthreads();
  for (int i = t; i < 4096; i += 256) ws[OFF_PH + bk * 4096 + i] = 0.f;
  if (w == 0){
    float fsum = accL[0][lane] + accL[1][lane] + accL[2][lane] + accL[3][lane];
    float cp  = ws[OFF_PCNT + (b * 64 + lane) * KK + k];
    float gp0 = ws[OFF_PGC + ((b * 64 + lane) * KK + k) * 3 + 0];
    float gp1 = ws[OFF_PGC + ((b * 64 + lane) * KK + k) * 3 + 1];
    float gp2 = ws[OFF_PGC + ((b * 64 + lane) * KK + k) * 3 + 2];
    #pragma unroll
    for (int off = 1; off < 64; off <<= 1){
      cp  += __shfl_xor(cp, off, 64);
      gp0 += __shfl_xor(gp0, off, 64);
      gp1 += __shfl_xor(gp1, off, 64);
      gp2 += __shfl_xor(gp2, off, 64);
    }
    float inv_c = FRCP(cp);
    float f = fsum * inv_c;
    ws[OFF_FC + (size_t)(b * KK + k) * DD + lane] = f;
    float n2 = f * f;
    #pragma unroll
    for (int off = 1; off < 64; off <<= 1) n2 += __shfl_xor(n2, off, 64);
    float fn = FSQRT(n2);
    float inv = FRCP(fmaxf(fn, 1e-12f));
    float ce = f * inv;
    ws[OFF_CEN + (size_t)(b * KK + k) * DD + lane] = ce;
    float g0 = gp0 * inv_c, g1 = gp1 * inv_c, g2 = gp2 * inv_c;
    if (lane == 0){
      ws[OFF_GC + (b * KK + k) * 3 + 0] = g0;
      ws[OFF_GC + (b * KK + k) * 3 + 1] = g1;
      ws[OFF_GC + (b * KK + k) * 3 + 2] = g2;
      ws[OFF_FCN  + b * KK + k] = fn;
      ws[OFF_FCN2 + b * KK + k] = n2;
      ws[OFF_CEN2 + b * KK + k] = n2 * inv * inv;
      ws[OFF_GC2  + b * KK + k] = g0 * g0 + g1 * g1 + g2 * g2;
      ws[OFF_CNTF + b * KK + k] = cp;
    }
  }
}

// Fused: blocks 0..63 = lovasz phase-1 point-major (1 thread/point, 16 k inner)
//        + var + center; blocks 64..639 = boundary 4-tile chunks.
__global__ __launch_bounds__(256, 4) void kfused(const int* __restrict__ lbl,
                                                 const ushort* __restrict__ EHg,
                                                 const float* __restrict__ pts,
                                                 float* __restrict__ ws){
  __shared__ float red[16];
  int t = threadIdx.x;

  if (blockIdx.x < NLOV){
    // ======== LOVASZ PHASE-1 (point-major) + VAR + CENTER ========
    __shared__ float invmfnS[KK], invfcS[KK], invCS[KK], fcn2S[KK], cen2S[KK], gc2S[KK];
    __shared__ float gcS[KK][3];
    int g = blockIdx.x * 256 + t;
    int b = g >> 12;
    int n = g & (NN - 1);
    if (t < KK){
      float fcn = ws[OFF_FCN + b * KK + t];
      invmfnS[t] = FRCP(fmaxf(fcn, 1e-8f));
      invfcS[t]  = FRCP(fmaxf(fcn, 1e-12f));
      invCS[t]   = FRCP(ws[OFF_CNTF + b * KK + t]);
      fcn2S[t]   = ws[OFF_FCN2 + b * KK + t];
      cen2S[t]   = ws[OFF_CEN2 + b * KK + t];
      gc2S[t]    = ws[OFF_GC2  + b * KK + t];
      gcS[t][0]  = ws[OFF_GC + (b * KK + t) * 3 + 0];
      gcS[t][1]  = ws[OFF_GC + (b * KK + t) * 3 + 1];
      gcS[t][2]  = ws[OFF_GC + (b * KK + t) * 3 + 2];
    }
    __syncthreads();

    const float* EN = ws + OFF_EMB + (size_t)(b * NN + n) * DD;
    float4 e4[16];
    #pragma unroll
    for (int i = 0; i < 16; i++) e4[i] = *(const float4*)&EN[i * 4];
    float nrm2 = ws[OFF_NRM2 + b * NN + n];
    float rs = FRSQ(nrm2);
    int l = lbl[b * NN + n];
    float p0 = pts[((size_t)b * NN + n) * 3 + 0];
    float p1 = pts[((size_t)b * NN + n) * 3 + 1];
    float p2 = pts[((size_t)b * NN + n) * 3 + 2];
    float p2sum = p0 * p0 + p1 * p1 + p2 * p2;
    float varA = 0.f, cenA = 0.f;

    for (int k = 0; k < KK; k++){
      const float* FCk = ws + OFF_FC + (size_t)(b * KK + k) * DD;  // block-uniform -> s_load
      float dx = 0.f, dy = 0.f, dz = 0.f, dw = 0.f;
      #pragma unroll
      for (int i = 0; i < 16; i++){
        float4 f = *(const float4*)&FCk[i * 4];
        dx += e4[i].x * f.x; dy += e4[i].y * f.y;
        dz += e4[i].z * f.z; dw += e4[i].w * f.w;
      }
      float dot = (dx + dy) + (dz + dw);
      float sim = dot * rs * invmfnS[k];
      int m = (l == k + 1) ? 1 : 0;
      if (sim > 0.f){
        int q = (int)(sim * (float)NBUCK);
        q = q > NBUCK - 1 ? NBUCK - 1 : q;
        int qi = NBUCK - 1 - q;
        unsigned* H = (unsigned*)(ws + OFF_PH) + (size_t)(b * KK + k) * 4096;
        float* S = ws + OFF_PH + (size_t)(b * KK + k) * 4096 + 2048;
        atomicAdd(&H[qi], 1u + ((unsigned)m << 16));
        atomicAdd(&S[qi], sim);
      }
      if (m){
        float dotc = dot * invfcS[k];
        float dnc = FSQRT(fmaxf(nrm2 + cen2S[k] - 2.f * dotc, 0.f));
        varA += fmaxf(dnc - 0.5f, 0.f) * invCS[k];
        float fd = FSQRT(fmaxf(nrm2 + fcn2S[k] - 2.f * dot, 0.f));
        float sd2 = p2sum + gc2S[k] - 2.f * (p0 * gcS[k][0] + p1 * gcS[k][1] + p2 * gcS[k][2]);
        cenA += FSQRT(fmaxf(sd2, 0.f)) * fd * invCS[k];
      }
    }
    float vs = blockReduceSum(varA, red);
    if (t == 0) ws[OFF_VAR + blockIdx.x] = vs;
    float cs = blockReduceSum(cenA, red);
    if (t == 0) ws[OFF_CENL + blockIdx.x] = cs;
  } else {
    // ================= BOUNDARY: 4-tile chunk =================
    int q = blockIdx.x - NLOV;
    int b = q / NCHB;
    int cq = q - b * NCHB;
    int ti = 0, rem = cq;
    while (rem >= ((32 - ti + 3) >> 2)){ rem -= (32 - ti + 3) >> 2; ti++; }
    int tj0 = ti + rem * 4;
    int nt = 32 - tj0; if (nt > 4) nt = 4;

    int lane = t & 63, w = t >> 6;
    int lm = lane & 15;
    int rif = (lane >> 4) * 4;
    int lk = (lane >> 4) * 8;
    const ushort* E = EHg + (size_t)b * NN * DD;
    const float* NR = ws + OFF_NRM2 + b * NN;
    const int* LB = lbl + b * NN;

    bf16x8 a[2][2];
    #pragma unroll
    for (int rb = 0; rb < 2; rb++)
      #pragma unroll
      for (int kh = 0; kh < 2; kh++)
        a[rb][kh] = *(const bf16x8*)&E[(size_t)(ti * 128 + w * 32 + rb * 16 + lm) * DD + kh * 32 + lk];

    float nAr[8]; int lAr[8];
    #pragma unroll
    for (int rb = 0; rb < 2; rb++)
      #pragma unroll
      for (int r = 0; r < 4; r++){
        int gi = ti * 128 + w * 32 + rb * 16 + rif + r;
        nAr[rb * 4 + r] = NR[gi];
        lAr[rb * 4 + r] = LB[gi];
      }

    float sum = 0.f;
    for (int tt = 0; tt < nt; tt++){
      int tj = tj0 + tt;
      bool diag = (tj == ti);
      #pragma unroll
      for (int pass = 0; pass < 2; pass++){
        float nBr[4]; int lBr[4];
        #pragma unroll
        for (int cb = 0; cb < 4; cb++){
          int gj = tj * 128 + (pass * 4 + cb) * 16 + lm;
          nBr[cb] = NR[gj];
          lBr[cb] = LB[gj];
        }
        f32x4 ac[2][4];
        #pragma unroll
        for (int rb = 0; rb < 2; rb++)
          #pragma unroll
          for (int cb = 0; cb < 4; cb++) ac[rb][cb] = (f32x4){0.f, 0.f, 0.f, 0.f};
        #pragma unroll
        for (int cb = 0; cb < 4; cb++){
          #pragma unroll
          for (int kh = 0; kh < 2; kh++){
            bf16x8 bb = *(const bf16x8*)&E[(size_t)(tj * 128 + (pass * 4 + cb) * 16 + lm) * DD + kh * 32 + lk];
            ac[0][cb] = __builtin_amdgcn_mfma_f32_16x16x32_bf16(a[0][kh], bb, ac[0][cb], 0, 0, 0);
            ac[1][cb] = __builtin_amdgcn_mfma_f32_16x16x32_bf16(a[1][kh], bb, ac[1][cb], 0, 0, 0);
          }
        }
        if (diag){
          #pragma unroll
          for (int rb = 0; rb < 2; rb++)
            #pragma unroll
            for (int cb = 0; cb < 4; cb++)
              #pragma unroll
              for (int r = 0; r < 4; r++){
                float d2 = fmaxf(nAr[rb * 4 + r] + nBr[cb] - 2.f * ac[rb][cb][r], 0.f);
                if (lAr[rb * 4 + r] == lBr[cb]) d2 = 0.f;
                float f = fmaxf(1.5f - FSQRT(d2), 0.f);
                int gi = w * 32 + rb * 16 + rif + r;
                int gj = (pass * 4 + cb) * 16 + lm;
                sum += (gi < gj) ? f : 0.f;
              }
        } else {
          #pragma unroll
          for (int rb = 0; rb < 2; rb++)
            #pragma unroll
            for (int cb = 0; cb < 4; cb++)
              #pragma unroll
              for (int r = 0; r < 4; r++){
                float d2 = fmaxf(nAr[rb * 4 + r] + nBr[cb] - 2.f * ac[rb][cb][r], 0.f);
                if (lAr[rb * 4 + r] == lBr[cb]) d2 = 0.f;
                sum += fmaxf(1.5f - FSQRT(d2), 0.f);
              }
        }
      }
    }
    float s = blockReduceSum(sum, red);
    if (t == 0) ws[OFF_BND + q] = s;
  }
}

// Lovasz phase-2: one block per (b,k) -- scan the global histogram.
__global__ void klov2(float* __restrict__ ws){
  __shared__ unsigned wsum[4];
  __shared__ float red[16];
  int bk = blockIdx.x;
  int b = bk >> 4, k = bk & 15;
  int t = threadIdx.x;
  int lane = t & 63, w = t >> 6;
  const unsigned* H = (const unsigned*)(ws + OFF_PH) + (size_t)bk * 4096;
  const float* S = ws + OFF_PH + (size_t)bk * 4096 + 2048;
  float C = ws[OFF_CNTF + b * KK + k];

  int base = t * 8;
  unsigned hv[8]; float sv[8];
  #pragma unroll
  for (int i = 0; i < 8; i++){ hv[i] = H[base + i]; sv[i] = S[base + i]; }
  unsigned loc[8];
  unsigned run = 0;
  #pragma unroll
  for (int i = 0; i < 8; i++){ loc[i] = run; run += hv[i]; }
  unsigned tot = run, sc = tot;
  #pragma unroll
  for (int off = 1; off < 64; off <<= 1){
    unsigned v = __shfl_up(sc, off, 64);
    if (lane >= off) sc += v;
  }
  if (lane == 63) wsum[w] = sc;
  __syncthreads();
  unsigned wbase = 0;
  #pragma unroll
  for (int w2 = 0; w2 < 4; w2++) if (w2 < w) wbase += wsum[w2];
  unsigned ex = wbase + sc - tot;

  float contrib = 0.f;
  #pragma unroll
  for (int i = 0; i < 8; i++){
    unsigned h = hv[i];
    unsigned g = h & 0xFFFFu, mu = h >> 16;
    if (g){
      unsigned pre = ex + loc[i];
      float i0 = (float)(pre & 0xFFFFu), c0 = (float)(pre >> 16);
      float i1 = i0 + (float)g, c1 = c0 + (float)mu;
      float jac0 = 1.f - (C - c0) * FRCP(C + i0 - c0);
      float jac1 = 1.f - (C - c1) * FRCP(C + i1 - c1);
      contrib += sv[i] * (jac1 - jac0) * FRCP((float)g);
    }
  }
  float ls = blockReduceSum(contrib, red);
  if (t == 0) ws[OFF_LOV + bk] = ls;
}

// Final: reduce scratch slots in double, dist/reg from CEN, combine.
__global__ void kfinal(const float* __restrict__ ws, float* __restrict__ out){
  __shared__ double dred[4];
  __shared__ float red[16];
  int t = threadIdx.x;
  double bs = 0.0;
  for (int i = t; i < NBND; i += 256) bs += (double)ws[OFF_BND + i];
  bs = blockReduceD(bs, dred);
  double lv = (t < 64) ? (double)ws[OFF_LOV + t] : 0.0;
  lv = blockReduceD(lv, dred);
  double va = (t < 64) ? (double)ws[OFF_VAR + t] : 0.0;
  va = blockReduceD(va, dred);
  double ce = (t < 64) ? (double)ws[OFF_CENL + t] : 0.0;
  ce = blockReduceD(ce, dred);

  double di = 0.0, rg = 0.0;
  int i = t >> 4, j = t & 15;
  for (int b = 0; b < BB; b++){
    float v = 0.f;
    if (i != j){
      float dot = 0.f;
      #pragma unroll
      for (int d = 0; d < DD; d++)
        dot += ws[OFF_CEN + (size_t)(b * KK + i) * DD + d] * ws[OFF_CEN + (size_t)(b * KK + j) * DD + d];
      float cd = FSQRT(fmaxf(ws[OFF_CEN2 + b * KK + i] + ws[OFF_CEN2 + b * KK + j] - 2.f * dot, 0.f));
      v = fmaxf(3.f - cd, 0.f);
    }
    float s = blockReduceSum(v, red);
    if (t == 0){
      di += (double)(s / 240.f);
      float s2 = 0.f;
      for (int k = 0; k < KK; k++) s2 += ws[OFF_CEN2 + b * KK + k];
      rg += (double)(FSQRT(s2) * 0.001f);
    }
  }
  if (t == 0){
    double var_l  = va / (4.0 + 1e-6);
    double dist_l = di / (4.0 + 1e-6);
    double reg_l  = rg / (4.0 + 1e-6);
    double cen_l  = ce / 4.0;
    double bnd_l  = (2.0 * bs + 1.5 * (double)NN * BB) / ((double)NN * NN * BB);
    double lov_l  = lv / 4.0;
    double total = 0.1 * (var_l + dist_l + reg_l) + 0.1 * cen_l + 0.05 * bnd_l + 0.01 * lov_l;
    out[0] = (float)total; out[1] = (float)var_l; out[2] = (float)dist_l;
    out[3] = (float)reg_l; out[4] = (float)cen_l; out[5] = (float)bnd_l;
    out[6] = (float)lov_l;
  }
}

extern "C" void kernel_launch(void* const* d_in, const int* in_sizes, int n_in,
                              void* d_out, int out_size, void* d_ws, size_t ws_size,
                              hipStream_t stream){
  const float* pts = (const float*)d_in[0];
  const float* emb = (const float*)d_in[1];
  const int* lbl   = (const int*)d_in[2];
  float* out = (float*)d_out;
  float* ws = (float*)d_ws;

  hipLaunchKernelGGL(knormacc, dim3(256), dim3(256), 0, stream, emb, pts, lbl, ws);
  hipLaunchKernelGGL(kcenters, dim3(64),  dim3(256), 0, stream, ws);
  hipLaunchKernelGGL(kfused,   dim3(NLOV + NBND), dim3(256), 0, stream,
                     lbl, (const ushort*)(ws + OFF_EMBH), pts, ws);
  hipLaunchKernelGGL(klov2,    dim3(64),  dim3(256), 0, stream, ws);
  hipLaunchKernelGGL(kfinal,   dim3(1),   dim3(256), 0, stream, ws, out);
}

// Round 16
// 75.295 us; speedup vs baseline: 2.9004x; 1.0255x over previous
//
#include <hip/hip_runtime.h>

#define BB 4
#define NN 4096
#define DD 64
#define KK 16
#define NBUCK 2048
#define NCHB 144              // boundary chunks per batch (4-tile chunks)
#define NBND (NCHB * BB)      // 576
#define NLOV 64               // lovasz point-major blocks (1 thread/point)
#define NBLK_NORM 512         // knormacc blocks (128/batch, 8 pts/wave) -- R9's
                              // isolated TLP change, now cleanly attributed

// ws float offsets (ws_size = 256 MiB, plenty)
#define OFF_EMB   0u          // B*N*D fp32 normalized emb
#define OFF_NRM2  1048576u    // B*N
#define OFF_PFC   1064960u    // 512*K*D = 524288
#define OFF_PGC   1589248u    // 512*K*3 = 24576
#define OFF_PCNT  1613824u    // 512*K = 8192
#define OFF_FC    1622016u    // B*K*D
#define OFF_CEN   1626112u    // B*K*D
#define OFF_GC    1630208u    // B*K*3
#define OFF_FCN   1630400u    // B*K
#define OFF_FCN2  1630464u
#define OFF_CEN2  1630528u
#define OFF_GC2   1630592u
#define OFF_CNTF  1630656u
#define OFF_BND   1630720u    // 576
#define OFF_VAR   1631296u    // 64
#define OFF_CENL  1631360u    // 64
#define OFF_LOV   1631424u    // 64
#define OFF_PH    1631744u    // 64 bk * 4096 (u32 hist[2048] + f32 ssum[2048])
#define OFF_EMBH  1894528u    // bf16 normalized emb (524288 float slots)

typedef __attribute__((ext_vector_type(8))) short bf16x8;
typedef __attribute__((ext_vector_type(4))) float f32x4;

#define FSQRT(x) __builtin_amdgcn_sqrtf(x)
#define FRCP(x)  __builtin_amdgcn_rcpf(x)
#define FRSQ(x)  __builtin_amdgcn_rsqf(x)

__device__ __forceinline__ ushort f2bf(float x){
  unsigned u = __float_as_uint(x);
  return (ushort)((u + 0x7FFFu + ((u >> 16) & 1u)) >> 16);
}

__device__ __forceinline__ float blockReduceSum(float v, float* sbuf){
  int t = threadIdx.x;
  #pragma unroll
  for (int off = 32; off > 0; off >>= 1) v += __shfl_xor(v, off, 64);
  if ((t & 63) == 0) sbuf[t >> 6] = v;
  __syncthreads();
  float s = 0.f;
  if (t == 0){
    int nw = blockDim.x >> 6;
    for (int i = 0; i < nw; i++) s += sbuf[i];
  }
  __syncthreads();
  return s;
}

__device__ __forceinline__ double blockReduceD(double v, double* sbuf){
  int t = threadIdx.x;
  #pragma unroll
  for (int off = 32; off > 0; off >>= 1) v += __shfl_xor(v, off, 64);
  if ((t & 63) == 0) sbuf[t >> 6] = v;
  __syncthreads();
  double s = 0.0;
  if (t == 0){
    for (int i = 0; i < 4; i++) s += sbuf[i];
  }
  __syncthreads();
  return s;
}

// Normalize embeddings, per-instance partial sums. 512 blocks (2/CU) for TLP.
__global__ void knormacc(const float* __restrict__ emb, const float* __restrict__ pts,
                         const int* __restrict__ lbl, float* __restrict__ ws){
  __shared__ float fcl[KK * DD];
  __shared__ float gcl[KK * 3];
  __shared__ float cntl[KK];
  int t = threadIdx.x;
  for (int i = t; i < KK * DD; i += 256) fcl[i] = 0.f;
  if (t < KK * 3) gcl[t] = 0.f;
  if (t < KK) cntl[t] = 0.f;
  __syncthreads();

  int lane = t & 63, w = t >> 6;
  int b = blockIdx.x >> 7;          // 128 blocks per batch
  int local = blockIdx.x & 127;
  int base = local * 32 + w * 8;
  const float* E = emb + (size_t)b * NN * DD;
  float* EN = ws + OFF_EMB + (size_t)b * NN * DD;
  ushort* EH = (ushort*)(ws + OFF_EMBH) + (size_t)b * NN * DD;

  for (int i = 0; i < 8; i++){
    int n = base + i;
    float v = E[(size_t)n * DD + lane];
    float ss = v * v;
    #pragma unroll
    for (int off = 1; off < 64; off <<= 1) ss += __shfl_xor(ss, off, 64);
    float nrm = FSQRT(ss);
    float scale = FRCP(fmaxf(nrm, 1e-12f));
    float vn = v * scale;
    EN[(size_t)n * DD + lane] = vn;
    EH[(size_t)n * DD + lane] = f2bf(vn);
    if (lane == 0) ws[OFF_NRM2 + b * NN + n] = ss * scale * scale;
    int l = lbl[b * NN + n];
    if (l >= 1 && l <= KK){
      int k = l - 1;
      atomicAdd(&fcl[k * DD + lane], vn);
      if (lane < 3) atomicAdd(&gcl[k * 3 + lane], pts[((size_t)b * NN + n) * 3 + lane]);
      if (lane == 0) atomicAdd(&cntl[k], 1.0f);
    }
  }
  __syncthreads();
  for (int i = t; i < KK * DD; i += 256)
    ws[OFF_PFC + (size_t)blockIdx.x * KK * DD + i] = fcl[i];
  if (t < KK * 3) ws[OFF_PGC + blockIdx.x * KK * 3 + t] = gcl[t];
  if (t < KK)     ws[OFF_PCNT + blockIdx.x * KK + t] = cntl[t];
}

// One block per (b,k): reduce 128 block-partials, finalize centers; zero PH slice.
__global__ void kcenters(float* __restrict__ ws){
  __shared__ float accL[4][DD];
  int bk = blockIdx.x;
  int b = bk >> 4, k = bk & 15;
  int t = threadIdx.x;
  int lane = t & 63, w = t >> 6;
  float s = 0.f;
  #pragma unroll
  for (int j = 0; j < 32; j++)
    s += ws[OFF_PFC + (size_t)((b * 128 + w * 32 + j) * KK + k) * DD + lane];
  accL[w][lane] = s;
  __syncthreads();
  for (int i = t; i < 4096; i += 256) ws[OFF_PH + bk * 4096 + i] = 0.f;
  if (w == 0){
    float fsum = accL[0][lane] + accL[1][lane] + accL[2][lane] + accL[3][lane];
    float cp  = ws[OFF_PCNT + (b * 128 + lane) * KK + k]
              + ws[OFF_PCNT + (b * 128 + 64 + lane) * KK + k];
    float gp0 = ws[OFF_PGC + ((b * 128 + lane) * KK + k) * 3 + 0]
              + ws[OFF_PGC + ((b * 128 + 64 + lane) * KK + k) * 3 + 0];
    float gp1 = ws[OFF_PGC + ((b * 128 + lane) * KK + k) * 3 + 1]
              + ws[OFF_PGC + ((b * 128 + 64 + lane) * KK + k) * 3 + 1];
    float gp2 = ws[OFF_PGC + ((b * 128 + lane) * KK + k) * 3 + 2]
              + ws[OFF_PGC + ((b * 128 + 64 + lane) * KK + k) * 3 + 2];
    #pragma unroll
    for (int off = 1; off < 64; off <<= 1){
      cp  += __shfl_xor(cp, off, 64);
      gp0 += __shfl_xor(gp0, off, 64);
      gp1 += __shfl_xor(gp1, off, 64);
      gp2 += __shfl_xor(gp2, off, 64);
    }
    float inv_c = FRCP(cp);
    float f = fsum * inv_c;
    ws[OFF_FC + (size_t)(b * KK + k) * DD + lane] = f;
    float n2 = f * f;
    #pragma unroll
    for (int off = 1; off < 64; off <<= 1) n2 += __shfl_xor(n2, off, 64);
    float fn = FSQRT(n2);
    float inv = FRCP(fmaxf(fn, 1e-12f));
    float ce = f * inv;
    ws[OFF_CEN + (size_t)(b * KK + k) * DD + lane] = ce;
    float g0 = gp0 * inv_c, g1 = gp1 * inv_c, g2 = gp2 * inv_c;
    if (lane == 0){
      ws[OFF_GC + (b * KK + k) * 3 + 0] = g0;
      ws[OFF_GC + (b * KK + k) * 3 + 1] = g1;
      ws[OFF_GC + (b * KK + k) * 3 + 2] = g2;
      ws[OFF_FCN  + b * KK + k] = fn;
      ws[OFF_FCN2 + b * KK + k] = n2;
      ws[OFF_CEN2 + b * KK + k] = n2 * inv * inv;
      ws[OFF_GC2  + b * KK + k] = g0 * g0 + g1 * g1 + g2 * g2;
      ws[OFF_CNTF + b * KK + k] = cp;
    }
  }
}

// Fused: blocks 0..63 = lovasz phase-1 point-major (1 thread/point, 16 k inner)
//        + var + center; blocks 64..639 = boundary 4-tile chunks.
// BYTE-IDENTICAL to R15 (best measured).
__global__ __launch_bounds__(256, 4) void kfused(const int* __restrict__ lbl,
                                                 const ushort* __restrict__ EHg,
                                                 const float* __restrict__ pts,
                                                 float* __restrict__ ws){
  __shared__ float red[16];
  int t = threadIdx.x;

  if (blockIdx.x < NLOV){
    // ======== LOVASZ PHASE-1 (point-major) + VAR + CENTER ========
    __shared__ float invmfnS[KK], invfcS[KK], invCS[KK], fcn2S[KK], cen2S[KK], gc2S[KK];
    __shared__ float gcS[KK][3];
    int g = blockIdx.x * 256 + t;
    int b = g >> 12;
    int n = g & (NN - 1);
    if (t < KK){
      float fcn = ws[OFF_FCN + b * KK + t];
      invmfnS[t] = FRCP(fmaxf(fcn, 1e-8f));
      invfcS[t]  = FRCP(fmaxf(fcn, 1e-12f));
      invCS[t]   = FRCP(ws[OFF_CNTF + b * KK + t]);
      fcn2S[t]   = ws[OFF_FCN2 + b * KK + t];
      cen2S[t]   = ws[OFF_CEN2 + b * KK + t];
      gc2S[t]    = ws[OFF_GC2  + b * KK + t];
      gcS[t][0]  = ws[OFF_GC + (b * KK + t) * 3 + 0];
      gcS[t][1]  = ws[OFF_GC + (b * KK + t) * 3 + 1];
      gcS[t][2]  = ws[OFF_GC + (b * KK + t) * 3 + 2];
    }
    __syncthreads();

    const float* EN = ws + OFF_EMB + (size_t)(b * NN + n) * DD;
    float4 e4[16];
    #pragma unroll
    for (int i = 0; i < 16; i++) e4[i] = *(const float4*)&EN[i * 4];
    float nrm2 = ws[OFF_NRM2 + b * NN + n];
    float rs = FRSQ(nrm2);
    int l = lbl[b * NN + n];
    float p0 = pts[((size_t)b * NN + n) * 3 + 0];
    float p1 = pts[((size_t)b * NN + n) * 3 + 1];
    float p2 = pts[((size_t)b * NN + n) * 3 + 2];
    float p2sum = p0 * p0 + p1 * p1 + p2 * p2;
    float varA = 0.f, cenA = 0.f;

    for (int k = 0; k < KK; k++){
      const float* FCk = ws + OFF_FC + (size_t)(b * KK + k) * DD;  // block-uniform -> s_load
      float dx = 0.f, dy = 0.f, dz = 0.f, dw = 0.f;
      #pragma unroll
      for (int i = 0; i < 16; i++){
        float4 f = *(const float4*)&FCk[i * 4];
        dx += e4[i].x * f.x; dy += e4[i].y * f.y;
        dz += e4[i].z * f.z; dw += e4[i].w * f.w;
      }
      float dot = (dx + dy) + (dz + dw);
      float sim = dot * rs * invmfnS[k];
      int m = (l == k + 1) ? 1 : 0;
      if (sim > 0.f){
        int q = (int)(sim * (float)NBUCK);
        q = q > NBUCK - 1 ? NBUCK - 1 : q;
        int qi = NBUCK - 1 - q;
        unsigned* H = (unsigned*)(ws + OFF_PH) + (size_t)(b * KK + k) * 4096;
        float* S = ws + OFF_PH + (size_t)(b * KK + k) * 4096 + 2048;
        atomicAdd(&H[qi], 1u + ((unsigned)m << 16));
        atomicAdd(&S[qi], sim);
      }
      if (m){
        float dotc = dot * invfcS[k];
        float dnc = FSQRT(fmaxf(nrm2 + cen2S[k] - 2.f * dotc, 0.f));
        varA += fmaxf(dnc - 0.5f, 0.f) * invCS[k];
        float fd = FSQRT(fmaxf(nrm2 + fcn2S[k] - 2.f * dot, 0.f));
        float sd2 = p2sum + gc2S[k] - 2.f * (p0 * gcS[k][0] + p1 * gcS[k][1] + p2 * gcS[k][2]);
        cenA += FSQRT(fmaxf(sd2, 0.f)) * fd * invCS[k];
      }
    }
    float vs = blockReduceSum(varA, red);
    if (t == 0) ws[OFF_VAR + blockIdx.x] = vs;
    float cs = blockReduceSum(cenA, red);
    if (t == 0) ws[OFF_CENL + blockIdx.x] = cs;
  } else {
    // ================= BOUNDARY: 4-tile chunk =================
    int q = blockIdx.x - NLOV;
    int b = q / NCHB;
    int cq = q - b * NCHB;
    int ti = 0, rem = cq;
    while (rem >= ((32 - ti + 3) >> 2)){ rem -= (32 - ti + 3) >> 2; ti++; }
    int tj0 = ti + rem * 4;
    int nt = 32 - tj0; if (nt > 4) nt = 4;

    int lane = t & 63, w = t >> 6;
    int lm = lane & 15;
    int rif = (lane >> 4) * 4;
    int lk = (lane >> 4) * 8;
    const ushort* E = EHg + (size_t)b * NN * DD;
    const float* NR = ws + OFF_NRM2 + b * NN;
    const int* LB = lbl + b * NN;

    bf16x8 a[2][2];
    #pragma unroll
    for (int rb = 0; rb < 2; rb++)
      #pragma unroll
      for (int kh = 0; kh < 2; kh++)
        a[rb][kh] = *(const bf16x8*)&E[(size_t)(ti * 128 + w * 32 + rb * 16 + lm) * DD + kh * 32 + lk];

    float nAr[8]; int lAr[8];
    #pragma unroll
    for (int rb = 0; rb < 2; rb++)
      #pragma unroll
      for (int r = 0; r < 4; r++){
        int gi = ti * 128 + w * 32 + rb * 16 + rif + r;
        nAr[rb * 4 + r] = NR[gi];
        lAr[rb * 4 + r] = LB[gi];
      }

    float sum = 0.f;
    for (int tt = 0; tt < nt; tt++){
      int tj = tj0 + tt;
      bool diag = (tj == ti);
      #pragma unroll
      for (int pass = 0; pass < 2; pass++){
        float nBr[4]; int lBr[4];
        #pragma unroll
        for (int cb = 0; cb < 4; cb++){
          int gj = tj * 128 + (pass * 4 + cb) * 16 + lm;
          nBr[cb] = NR[gj];
          lBr[cb] = LB[gj];
        }
        f32x4 ac[2][4];
        #pragma unroll
        for (int rb = 0; rb < 2; rb++)
          #pragma unroll
          for (int cb = 0; cb < 4; cb++) ac[rb][cb] = (f32x4){0.f, 0.f, 0.f, 0.f};
        #pragma unroll
        for (int cb = 0; cb < 4; cb++){
          #pragma unroll
          for (int kh = 0; kh < 2; kh++){
            bf16x8 bb = *(const bf16x8*)&E[(size_t)(tj * 128 + (pass * 4 + cb) * 16 + lm) * DD + kh * 32 + lk];
            ac[0][cb] = __builtin_amdgcn_mfma_f32_16x16x32_bf16(a[0][kh], bb, ac[0][cb], 0, 0, 0);
            ac[1][cb] = __builtin_amdgcn_mfma_f32_16x16x32_bf16(a[1][kh], bb, ac[1][cb], 0, 0, 0);
          }
        }
        if (diag){
          #pragma unroll
          for (int rb = 0; rb < 2; rb++)
            #pragma unroll
            for (int cb = 0; cb < 4; cb++)
              #pragma unroll
              for (int r = 0; r < 4; r++){
                float d2 = fmaxf(nAr[rb * 4 + r] + nBr[cb] - 2.f * ac[rb][cb][r], 0.f);
                if (lAr[rb * 4 + r] == lBr[cb]) d2 = 0.f;
                float f = fmaxf(1.5f - FSQRT(d2), 0.f);
                int gi = w * 32 + rb * 16 + rif + r;
                int gj = (pass * 4 + cb) * 16 + lm;
                sum += (gi < gj) ? f : 0.f;
              }
        } else {
          #pragma unroll
          for (int rb = 0; rb < 2; rb++)
            #pragma unroll
            for (int cb = 0; cb < 4; cb++)
              #pragma unroll
              for (int r = 0; r < 4; r++){
                float d2 = fmaxf(nAr[rb * 4 + r] + nBr[cb] - 2.f * ac[rb][cb][r], 0.f);
                if (lAr[rb * 4 + r] == lBr[cb]) d2 = 0.f;
                sum += fmaxf(1.5f - FSQRT(d2), 0.f);
              }
        }
      }
    }
    float s = blockReduceSum(sum, red);
    if (t == 0) ws[OFF_BND + q] = s;
  }
}

// Lovasz phase-2: one block per (b,k) -- scan the global histogram.
__global__ void klov2(float* __restrict__ ws){
  __shared__ unsigned wsum[4];
  __shared__ float red[16];
  int bk = blockIdx.x;
  int b = bk >> 4, k = bk & 15;
  int t = threadIdx.x;
  int lane = t & 63, w = t >> 6;
  const unsigned* H = (const unsigned*)(ws + OFF_PH) + (size_t)bk * 4096;
  const float* S = ws + OFF_PH + (size_t)bk * 4096 + 2048;
  float C = ws[OFF_CNTF + b * KK + k];

  int base = t * 8;
  unsigned hv[8]; float sv[8];
  #pragma unroll
  for (int i = 0; i < 8; i++){ hv[i] = H[base + i]; sv[i] = S[base + i]; }
  unsigned loc[8];
  unsigned run = 0;
  #pragma unroll
  for (int i = 0; i < 8; i++){ loc[i] = run; run += hv[i]; }
  unsigned tot = run, sc = tot;
  #pragma unroll
  for (int off = 1; off < 64; off <<= 1){
    unsigned v = __shfl_up(sc, off, 64);
    if (lane >= off) sc += v;
  }
  if (lane == 63) wsum[w] = sc;
  __syncthreads();
  unsigned wbase = 0;
  #pragma unroll
  for (int w2 = 0; w2 < 4; w2++) if (w2 < w) wbase += wsum[w2];
  unsigned ex = wbase + sc - tot;

  float contrib = 0.f;
  #pragma unroll
  for (int i = 0; i < 8; i++){
    unsigned h = hv[i];
    unsigned g = h & 0xFFFFu, mu = h >> 16;
    if (g){
      unsigned pre = ex + loc[i];
      float i0 = (float)(pre & 0xFFFFu), c0 = (float)(pre >> 16);
      float i1 = i0 + (float)g, c1 = c0 + (float)mu;
      float jac0 = 1.f - (C - c0) * FRCP(C + i0 - c0);
      float jac1 = 1.f - (C - c1) * FRCP(C + i1 - c1);
      contrib += sv[i] * (jac1 - jac0) * FRCP((float)g);
    }
  }
  float ls = blockReduceSum(contrib, red);
  if (t == 0) ws[OFF_LOV + bk] = ls;
}

// Final: reduce scratch slots in double, dist/reg from CEN, combine.
__global__ void kfinal(const float* __restrict__ ws, float* __restrict__ out){
  __shared__ double dred[4];
  __shared__ float red[16];
  int t = threadIdx.x;
  double bs = 0.0;
  for (int i = t; i < NBND; i += 256) bs += (double)ws[OFF_BND + i];
  bs = blockReduceD(bs, dred);
  double lv = (t < 64) ? (double)ws[OFF_LOV + t] : 0.0;
  lv = blockReduceD(lv, dred);
  double va = (t < 64) ? (double)ws[OFF_VAR + t] : 0.0;
  va = blockReduceD(va, dred);
  double ce = (t < 64) ? (double)ws[OFF_CENL + t] : 0.0;
  ce = blockReduceD(ce, dred);

  double di = 0.0, rg = 0.0;
  int i = t >> 4, j = t & 15;
  for (int b = 0; b < BB; b++){
    float v = 0.f;
    if (i != j){
      float dot = 0.f;
      #pragma unroll
      for (int d = 0; d < DD; d++)
        dot += ws[OFF_CEN + (size_t)(b * KK + i) * DD + d] * ws[OFF_CEN + (size_t)(b * KK + j) * DD + d];
      float cd = FSQRT(fmaxf(ws[OFF_CEN2 + b * KK + i] + ws[OFF_CEN2 + b * KK + j] - 2.f * dot, 0.f));
      v = fmaxf(3.f - cd, 0.f);
    }
    float s = blockReduceSum(v, red);
    if (t == 0){
      di += (double)(s / 240.f);
      float s2 = 0.f;
      for (int k = 0; k < KK; k++) s2 += ws[OFF_CEN2 + b * KK + k];
      rg += (double)(FSQRT(s2) * 0.001f);
    }
  }
  if (t == 0){
    double var_l  = va / (4.0 + 1e-6);
    double dist_l = di / (4.0 + 1e-6);
    double reg_l  = rg / (4.0 + 1e-6);
    double cen_l  = ce / 4.0;
    double bnd_l  = (2.0 * bs + 1.5 * (double)NN * BB) / ((double)NN * NN * BB);
    double lov_l  = lv / 4.0;
    double total = 0.1 * (var_l + dist_l + reg_l) + 0.1 * cen_l + 0.05 * bnd_l + 0.01 * lov_l;
    out[0] = (float)total; out[1] = (float)var_l; out[2] = (float)dist_l;
    out[3] = (float)reg_l; out[4] = (float)cen_l; out[5] = (float)bnd_l;
    out[6] = (float)lov_l;
  }
}

extern "C" void kernel_launch(void* const* d_in, const int* in_sizes, int n_in,
                              void* d_out, int out_size, void* d_ws, size_t ws_size,
                              hipStream_t stream){
  const float* pts = (const float*)d_in[0];
  const float* emb = (const float*)d_in[1];
  const int* lbl   = (const int*)d_in[2];
  float* out = (float*)d_out;
  float* ws = (float*)d_ws;

  hipLaunchKernelGGL(knormacc, dim3(NBLK_NORM), dim3(256), 0, stream, emb, pts, lbl, ws);
  hipLaunchKernelGGL(kcenters, dim3(64),  dim3(256), 0, stream, ws);
  hipLaunchKernelGGL(kfused,   dim3(NLOV + NBND), dim3(256), 0, stream,
                     lbl, (const ushort*)(ws + OFF_EMBH), pts, ws);
  hipLaunchKernelGGL(klov2,    dim3(64),  dim3(256), 0, stream, ws);
  hipLaunchKernelGGL(kfinal,   dim3(1),   dim3(256), 0, stream, ws, out);
}

// Round 17
// 73.976 us; speedup vs baseline: 2.9521x; 1.0178x over previous
//
#include <hip/hip_runtime.h>

#define BB 4
#define NN 4096
#define DD 64
#define KK 16
#define NBUCK 2048
#define NCHB 144              // boundary chunks per batch (4-tile chunks)
#define NBND (NCHB * BB)      // 576
#define NLOV 128              // lovasz phase-1 blocks: 64 point-groups x 2 k-halves
#define NBLK_NORM 512         // knormacc blocks (128/batch, 8 pts/wave)

// ws float offsets (ws_size = 256 MiB, plenty)
#define OFF_EMB   0u          // B*N*D fp32 normalized emb
#define OFF_NRM2  1048576u    // B*N
#define OFF_PFC   1064960u    // 512*K*D = 524288
#define OFF_PGC   1589248u    // 512*K*3 = 24576
#define OFF_PCNT  1613824u    // 512*K = 8192
#define OFF_FC    1622016u    // B*K*D
#define OFF_CEN   1626112u    // B*K*D
#define OFF_GC    1630208u    // B*K*3
#define OFF_FCN   1630400u    // B*K
#define OFF_FCN2  1630464u
#define OFF_CEN2  1630528u
#define OFF_GC2   1630592u
#define OFF_CNTF  1630656u
#define OFF_BND   1630720u    // 576
#define OFF_VAR   1631296u    // 128
#define OFF_CENL  1631424u    // 128
#define OFF_LOV   1631552u    // 64
#define OFF_PH    1631744u    // 64 bk * 4096 (u32 hist[2048] + f32 ssum[2048])
#define OFF_EMBH  1894528u    // bf16 normalized emb (524288 float slots)

typedef __attribute__((ext_vector_type(8))) short bf16x8;
typedef __attribute__((ext_vector_type(4))) float f32x4;

#define FSQRT(x) __builtin_amdgcn_sqrtf(x)
#define FRCP(x)  __builtin_amdgcn_rcpf(x)
#define FRSQ(x)  __builtin_amdgcn_rsqf(x)

__device__ __forceinline__ ushort f2bf(float x){
  unsigned u = __float_as_uint(x);
  return (ushort)((u + 0x7FFFu + ((u >> 16) & 1u)) >> 16);
}

__device__ __forceinline__ float blockReduceSum(float v, float* sbuf){
  int t = threadIdx.x;
  #pragma unroll
  for (int off = 32; off > 0; off >>= 1) v += __shfl_xor(v, off, 64);
  if ((t & 63) == 0) sbuf[t >> 6] = v;
  __syncthreads();
  float s = 0.f;
  if (t == 0){
    int nw = blockDim.x >> 6;
    for (int i = 0; i < nw; i++) s += sbuf[i];
  }
  __syncthreads();
  return s;
}

__device__ __forceinline__ double blockReduceD(double v, double* sbuf){
  int t = threadIdx.x;
  #pragma unroll
  for (int off = 32; off > 0; off >>= 1) v += __shfl_xor(v, off, 64);
  if ((t & 63) == 0) sbuf[t >> 6] = v;
  __syncthreads();
  double s = 0.0;
  if (t == 0){
    for (int i = 0; i < 4; i++) s += sbuf[i];
  }
  __syncthreads();
  return s;
}

// Normalize embeddings, per-instance partial sums. 512 blocks (2/CU) for TLP.
__global__ void knormacc(const float* __restrict__ emb, const float* __restrict__ pts,
                         const int* __restrict__ lbl, float* __restrict__ ws){
  __shared__ float fcl[KK * DD];
  __shared__ float gcl[KK * 3];
  __shared__ float cntl[KK];
  int t = threadIdx.x;
  for (int i = t; i < KK * DD; i += 256) fcl[i] = 0.f;
  if (t < KK * 3) gcl[t] = 0.f;
  if (t < KK) cntl[t] = 0.f;
  __syncthreads();

  int lane = t & 63, w = t >> 6;
  int b = blockIdx.x >> 7;          // 128 blocks per batch
  int local = blockIdx.x & 127;
  int base = local * 32 + w * 8;
  const float* E = emb + (size_t)b * NN * DD;
  float* EN = ws + OFF_EMB + (size_t)b * NN * DD;
  ushort* EH = (ushort*)(ws + OFF_EMBH) + (size_t)b * NN * DD;

  for (int i = 0; i < 8; i++){
    int n = base + i;
    float v = E[(size_t)n * DD + lane];
    float ss = v * v;
    #pragma unroll
    for (int off = 1; off < 64; off <<= 1) ss += __shfl_xor(ss, off, 64);
    float nrm = FSQRT(ss);
    float scale = FRCP(fmaxf(nrm, 1e-12f));
    float vn = v * scale;
    EN[(size_t)n * DD + lane] = vn;
    EH[(size_t)n * DD + lane] = f2bf(vn);
    if (lane == 0) ws[OFF_NRM2 + b * NN + n] = ss * scale * scale;
    int l = lbl[b * NN + n];
    if (l >= 1 && l <= KK){
      int k = l - 1;
      atomicAdd(&fcl[k * DD + lane], vn);
      if (lane < 3) atomicAdd(&gcl[k * 3 + lane], pts[((size_t)b * NN + n) * 3 + lane]);
      if (lane == 0) atomicAdd(&cntl[k], 1.0f);
    }
  }
  __syncthreads();
  for (int i = t; i < KK * DD; i += 256)
    ws[OFF_PFC + (size_t)blockIdx.x * KK * DD + i] = fcl[i];
  if (t < KK * 3) ws[OFF_PGC + blockIdx.x * KK * 3 + t] = gcl[t];
  if (t < KK)     ws[OFF_PCNT + blockIdx.x * KK + t] = cntl[t];
}

// One block per (b,k): reduce 128 block-partials, finalize centers; zero PH slice.
__global__ void kcenters(float* __restrict__ ws){
  __shared__ float accL[4][DD];
  int bk = blockIdx.x;
  int b = bk >> 4, k = bk & 15;
  int t = threadIdx.x;
  int lane = t & 63, w = t >> 6;
  float s = 0.f;
  #pragma unroll
  for (int j = 0; j < 32; j++)
    s += ws[OFF_PFC + (size_t)((b * 128 + w * 32 + j) * KK + k) * DD + lane];
  accL[w][lane] = s;
  __syncthreads();
  for (int i = t; i < 4096; i += 256) ws[OFF_PH + bk * 4096 + i] = 0.f;
  if (w == 0){
    float fsum = accL[0][lane] + accL[1][lane] + accL[2][lane] + accL[3][lane];
    float cp  = ws[OFF_PCNT + (b * 128 + lane) * KK + k]
              + ws[OFF_PCNT + (b * 128 + 64 + lane) * KK + k];
    float gp0 = ws[OFF_PGC + ((b * 128 + lane) * KK + k) * 3 + 0]
              + ws[OFF_PGC + ((b * 128 + 64 + lane) * KK + k) * 3 + 0];
    float gp1 = ws[OFF_PGC + ((b * 128 + lane) * KK + k) * 3 + 1]
              + ws[OFF_PGC + ((b * 128 + 64 + lane) * KK + k) * 3 + 1];
    float gp2 = ws[OFF_PGC + ((b * 128 + lane) * KK + k) * 3 + 2]
              + ws[OFF_PGC + ((b * 128 + 64 + lane) * KK + k) * 3 + 2];
    #pragma unroll
    for (int off = 1; off < 64; off <<= 1){
      cp  += __shfl_xor(cp, off, 64);
      gp0 += __shfl_xor(gp0, off, 64);
      gp1 += __shfl_xor(gp1, off, 64);
      gp2 += __shfl_xor(gp2, off, 64);
    }
    float inv_c = FRCP(cp);
    float f = fsum * inv_c;
    ws[OFF_FC + (size_t)(b * KK + k) * DD + lane] = f;
    float n2 = f * f;
    #pragma unroll
    for (int off = 1; off < 64; off <<= 1) n2 += __shfl_xor(n2, off, 64);
    float fn = FSQRT(n2);
    float inv = FRCP(fmaxf(fn, 1e-12f));
    float ce = f * inv;
    ws[OFF_CEN + (size_t)(b * KK + k) * DD + lane] = ce;
    float g0 = gp0 * inv_c, g1 = gp1 * inv_c, g2 = gp2 * inv_c;
    if (lane == 0){
      ws[OFF_GC + (b * KK + k) * 3 + 0] = g0;
      ws[OFF_GC + (b * KK + k) * 3 + 1] = g1;
      ws[OFF_GC + (b * KK + k) * 3 + 2] = g2;
      ws[OFF_FCN  + b * KK + k] = fn;
      ws[OFF_FCN2 + b * KK + k] = n2;
      ws[OFF_CEN2 + b * KK + k] = n2 * inv * inv;
      ws[OFF_GC2  + b * KK + k] = g0 * g0 + g1 * g1 + g2 * g2;
      ws[OFF_CNTF + b * KK + k] = cp;
    }
  }
}

// Fused: blocks 0..127 = lovasz phase-1, point-major, k SPLIT 2-way
//        (block = point-group g = blk>>1, k-half = blk&1, 8 k's each);
//        blocks 128..703 = boundary 4-tile chunks (byte-identical to R16).
__global__ __launch_bounds__(256, 4) void kfused(const int* __restrict__ lbl,
                                                 const ushort* __restrict__ EHg,
                                                 const float* __restrict__ pts,
                                                 float* __restrict__ ws){
  __shared__ float red[16];
  int t = threadIdx.x;

  if (blockIdx.x < NLOV){
    // ======== LOVASZ PHASE-1 (point-major, 8 k's per block) + VAR + CENTER ====
    __shared__ float invmfnS[KK], invfcS[KK], invCS[KK], fcn2S[KK], cen2S[KK], gc2S[KK];
    __shared__ float gcS[KK][3];
    int pg = blockIdx.x >> 1;        // point-group 0..63
    int kh2 = blockIdx.x & 1;        // k-half
    int k0 = kh2 * 8;
    int g = pg * 256 + t;
    int b = g >> 12;
    int n = g & (NN - 1);
    if (t < KK){
      float fcn = ws[OFF_FCN + b * KK + t];
      invmfnS[t] = FRCP(fmaxf(fcn, 1e-8f));
      invfcS[t]  = FRCP(fmaxf(fcn, 1e-12f));
      invCS[t]   = FRCP(ws[OFF_CNTF + b * KK + t]);
      fcn2S[t]   = ws[OFF_FCN2 + b * KK + t];
      cen2S[t]   = ws[OFF_CEN2 + b * KK + t];
      gc2S[t]    = ws[OFF_GC2  + b * KK + t];
      gcS[t][0]  = ws[OFF_GC + (b * KK + t) * 3 + 0];
      gcS[t][1]  = ws[OFF_GC + (b * KK + t) * 3 + 1];
      gcS[t][2]  = ws[OFF_GC + (b * KK + t) * 3 + 2];
    }
    __syncthreads();

    const float* EN = ws + OFF_EMB + (size_t)(b * NN + n) * DD;
    float4 e4[16];
    #pragma unroll
    for (int i = 0; i < 16; i++) e4[i] = *(const float4*)&EN[i * 4];
    float nrm2 = ws[OFF_NRM2 + b * NN + n];
    float rs = FRSQ(nrm2);
    int l = lbl[b * NN + n];
    float p0 = pts[((size_t)b * NN + n) * 3 + 0];
    float p1 = pts[((size_t)b * NN + n) * 3 + 1];
    float p2 = pts[((size_t)b * NN + n) * 3 + 2];
    float p2sum = p0 * p0 + p1 * p1 + p2 * p2;
    float varA = 0.f, cenA = 0.f;

    for (int kk = 0; kk < 8; kk++){
      int k = k0 + kk;
      const float* FCk = ws + OFF_FC + (size_t)(b * KK + k) * DD;  // block-uniform -> s_load
      float dx = 0.f, dy = 0.f, dz = 0.f, dw = 0.f;
      #pragma unroll
      for (int i = 0; i < 16; i++){
        float4 f = *(const float4*)&FCk[i * 4];
        dx += e4[i].x * f.x; dy += e4[i].y * f.y;
        dz += e4[i].z * f.z; dw += e4[i].w * f.w;
      }
      float dot = (dx + dy) + (dz + dw);
      float sim = dot * rs * invmfnS[k];
      int m = (l == k + 1) ? 1 : 0;
      if (sim > 0.f){
        int q = (int)(sim * (float)NBUCK);
        q = q > NBUCK - 1 ? NBUCK - 1 : q;
        int qi = NBUCK - 1 - q;
        unsigned* H = (unsigned*)(ws + OFF_PH) + (size_t)(b * KK + k) * 4096;
        float* S = ws + OFF_PH + (size_t)(b * KK + k) * 4096 + 2048;
        atomicAdd(&H[qi], 1u + ((unsigned)m << 16));
        atomicAdd(&S[qi], sim);
      }
      if (m){
        float dotc = dot * invfcS[k];
        float dnc = FSQRT(fmaxf(nrm2 + cen2S[k] - 2.f * dotc, 0.f));
        varA += fmaxf(dnc - 0.5f, 0.f) * invCS[k];
        float fd = FSQRT(fmaxf(nrm2 + fcn2S[k] - 2.f * dot, 0.f));
        float sd2 = p2sum + gc2S[k] - 2.f * (p0 * gcS[k][0] + p1 * gcS[k][1] + p2 * gcS[k][2]);
        cenA += FSQRT(fmaxf(sd2, 0.f)) * fd * invCS[k];
      }
    }
    float vs = blockReduceSum(varA, red);
    if (t == 0) ws[OFF_VAR + blockIdx.x] = vs;
    float cs = blockReduceSum(cenA, red);
    if (t == 0) ws[OFF_CENL + blockIdx.x] = cs;
  } else {
    // ================= BOUNDARY: 4-tile chunk (byte-identical to R16) =========
    int q = blockIdx.x - NLOV;
    int b = q / NCHB;
    int cq = q - b * NCHB;
    int ti = 0, rem = cq;
    while (rem >= ((32 - ti + 3) >> 2)){ rem -= (32 - ti + 3) >> 2; ti++; }
    int tj0 = ti + rem * 4;
    int nt = 32 - tj0; if (nt > 4) nt = 4;

    int lane = t & 63, w = t >> 6;
    int lm = lane & 15;
    int rif = (lane >> 4) * 4;
    int lk = (lane >> 4) * 8;
    const ushort* E = EHg + (size_t)b * NN * DD;
    const float* NR = ws + OFF_NRM2 + b * NN;
    const int* LB = lbl + b * NN;

    bf16x8 a[2][2];
    #pragma unroll
    for (int rb = 0; rb < 2; rb++)
      #pragma unroll
      for (int kh = 0; kh < 2; kh++)
        a[rb][kh] = *(const bf16x8*)&E[(size_t)(ti * 128 + w * 32 + rb * 16 + lm) * DD + kh * 32 + lk];

    float nAr[8]; int lAr[8];
    #pragma unroll
    for (int rb = 0; rb < 2; rb++)
      #pragma unroll
      for (int r = 0; r < 4; r++){
        int gi = ti * 128 + w * 32 + rb * 16 + rif + r;
        nAr[rb * 4 + r] = NR[gi];
        lAr[rb * 4 + r] = LB[gi];
      }

    float sum = 0.f;
    for (int tt = 0; tt < nt; tt++){
      int tj = tj0 + tt;
      bool diag = (tj == ti);
      #pragma unroll
      for (int pass = 0; pass < 2; pass++){
        float nBr[4]; int lBr[4];
        #pragma unroll
        for (int cb = 0; cb < 4; cb++){
          int gj = tj * 128 + (pass * 4 + cb) * 16 + lm;
          nBr[cb] = NR[gj];
          lBr[cb] = LB[gj];
        }
        f32x4 ac[2][4];
        #pragma unroll
        for (int rb = 0; rb < 2; rb++)
          #pragma unroll
          for (int cb = 0; cb < 4; cb++) ac[rb][cb] = (f32x4){0.f, 0.f, 0.f, 0.f};
        #pragma unroll
        for (int cb = 0; cb < 4; cb++){
          #pragma unroll
          for (int kh = 0; kh < 2; kh++){
            bf16x8 bb = *(const bf16x8*)&E[(size_t)(tj * 128 + (pass * 4 + cb) * 16 + lm) * DD + kh * 32 + lk];
            ac[0][cb] = __builtin_amdgcn_mfma_f32_16x16x32_bf16(a[0][kh], bb, ac[0][cb], 0, 0, 0);
            ac[1][cb] = __builtin_amdgcn_mfma_f32_16x16x32_bf16(a[1][kh], bb, ac[1][cb], 0, 0, 0);
          }
        }
        if (diag){
          #pragma unroll
          for (int rb = 0; rb < 2; rb++)
            #pragma unroll
            for (int cb = 0; cb < 4; cb++)
              #pragma unroll
              for (int r = 0; r < 4; r++){
                float d2 = fmaxf(nAr[rb * 4 + r] + nBr[cb] - 2.f * ac[rb][cb][r], 0.f);
                if (lAr[rb * 4 + r] == lBr[cb]) d2 = 0.f;
                float f = fmaxf(1.5f - FSQRT(d2), 0.f);
                int gi = w * 32 + rb * 16 + rif + r;
                int gj = (pass * 4 + cb) * 16 + lm;
                sum += (gi < gj) ? f : 0.f;
              }
        } else {
          #pragma unroll
          for (int rb = 0; rb < 2; rb++)
            #pragma unroll
            for (int cb = 0; cb < 4; cb++)
              #pragma unroll
              for (int r = 0; r < 4; r++){
                float d2 = fmaxf(nAr[rb * 4 + r] + nBr[cb] - 2.f * ac[rb][cb][r], 0.f);
                if (lAr[rb * 4 + r] == lBr[cb]) d2 = 0.f;
                sum += fmaxf(1.5f - FSQRT(d2), 0.f);
              }
        }
      }
    }
    float s = blockReduceSum(sum, red);
    if (t == 0) ws[OFF_BND + q] = s;
  }
}

// Lovasz phase-2: one block per (b,k) -- scan the global histogram.
__global__ void klov2(float* __restrict__ ws){
  __shared__ unsigned wsum[4];
  __shared__ float red[16];
  int bk = blockIdx.x;
  int b = bk >> 4, k = bk & 15;
  int t = threadIdx.x;
  int lane = t & 63, w = t >> 6;
  const unsigned* H = (const unsigned*)(ws + OFF_PH) + (size_t)bk * 4096;
  const float* S = ws + OFF_PH + (size_t)bk * 4096 + 2048;
  float C = ws[OFF_CNTF + b * KK + k];

  int base = t * 8;
  unsigned hv[8]; float sv[8];
  #pragma unroll
  for (int i = 0; i < 8; i++){ hv[i] = H[base + i]; sv[i] = S[base + i]; }
  unsigned loc[8];
  unsigned run = 0;
  #pragma unroll
  for (int i = 0; i < 8; i++){ loc[i] = run; run += hv[i]; }
  unsigned tot = run, sc = tot;
  #pragma unroll
  for (int off = 1; off < 64; off <<= 1){
    unsigned v = __shfl_up(sc, off, 64);
    if (lane >= off) sc += v;
  }
  if (lane == 63) wsum[w] = sc;
  __syncthreads();
  unsigned wbase = 0;
  #pragma unroll
  for (int w2 = 0; w2 < 4; w2++) if (w2 < w) wbase += wsum[w2];
  unsigned ex = wbase + sc - tot;

  float contrib = 0.f;
  #pragma unroll
  for (int i = 0; i < 8; i++){
    unsigned h = hv[i];
    unsigned g = h & 0xFFFFu, mu = h >> 16;
    if (g){
      unsigned pre = ex + loc[i];
      float i0 = (float)(pre & 0xFFFFu), c0 = (float)(pre >> 16);
      float i1 = i0 + (float)g, c1 = c0 + (float)mu;
      float jac0 = 1.f - (C - c0) * FRCP(C + i0 - c0);
      float jac1 = 1.f - (C - c1) * FRCP(C + i1 - c1);
      contrib += sv[i] * (jac1 - jac0) * FRCP((float)g);
    }
  }
  float ls = blockReduceSum(contrib, red);
  if (t == 0) ws[OFF_LOV + bk] = ls;
}

// Final: reduce scratch slots in double, dist/reg from CEN, combine.
__global__ void kfinal(const float* __restrict__ ws, float* __restrict__ out){
  __shared__ double dred[4];
  __shared__ float red[16];
  int t = threadIdx.x;
  double bs = 0.0;
  for (int i = t; i < NBND; i += 256) bs += (double)ws[OFF_BND + i];
  bs = blockReduceD(bs, dred);
  double lv = (t < 64) ? (double)ws[OFF_LOV + t] : 0.0;
  lv = blockReduceD(lv, dred);
  double va = (t < 128) ? (double)ws[OFF_VAR + t] : 0.0;
  va = blockReduceD(va, dred);
  double ce = (t < 128) ? (double)ws[OFF_CENL + t] : 0.0;
  ce = blockReduceD(ce, dred);

  double di = 0.0, rg = 0.0;
  int i = t >> 4, j = t & 15;
  for (int b = 0; b < BB; b++){
    float v = 0.f;
    if (i != j){
      float dot = 0.f;
      #pragma unroll
      for (int d = 0; d < DD; d++)
        dot += ws[OFF_CEN + (size_t)(b * KK + i) * DD + d] * ws[OFF_CEN + (size_t)(b * KK + j) * DD + d];
      float cd = FSQRT(fmaxf(ws[OFF_CEN2 + b * KK + i] + ws[OFF_CEN2 + b * KK + j] - 2.f * dot, 0.f));
      v = fmaxf(3.f - cd, 0.f);
    }
    float s = blockReduceSum(v, red);
    if (t == 0){
      di += (double)(s / 240.f);
      float s2 = 0.f;
      for (int k = 0; k < KK; k++) s2 += ws[OFF_CEN2 + b * KK + k];
      rg += (double)(FSQRT(s2) * 0.001f);
    }
  }
  if (t == 0){
    double var_l  = va / (4.0 + 1e-6);
    double dist_l = di / (4.0 + 1e-6);
    double reg_l  = rg / (4.0 + 1e-6);
    double cen_l  = ce / 4.0;
    double bnd_l  = (2.0 * bs + 1.5 * (double)NN * BB) / ((double)NN * NN * BB);
    double lov_l  = lv / 4.0;
    double total = 0.1 * (var_l + dist_l + reg_l) + 0.1 * cen_l + 0.05 * bnd_l + 0.01 * lov_l;
    out[0] = (float)total; out[1] = (float)var_l; out[2] = (float)dist_l;
    out[3] = (float)reg_l; out[4] = (float)cen_l; out[5] = (float)bnd_l;
    out[6] = (float)lov_l;
  }
}

extern "C" void kernel_launch(void* const* d_in, const int* in_sizes, int n_in,
                              void* d_out, int out_size, void* d_ws, size_t ws_size,
                              hipStream_t stream){
  const float* pts = (const float*)d_in[0];
  const float* emb = (const float*)d_in[1];
  const int* lbl   = (const int*)d_in[2];
  float* out = (float*)d_out;
  float* ws = (float*)d_ws;

  hipLaunchKernelGGL(knormacc, dim3(NBLK_NORM), dim3(256), 0, stream, emb, pts, lbl, ws);
  hipLaunchKernelGGL(kcenters, dim3(64),  dim3(256), 0, stream, ws);
  hipLaunchKernelGGL(kfused,   dim3(NLOV + NBND), dim3(256), 0, stream,
                     lbl, (const ushort*)(ws + OFF_EMBH), pts, ws);
  hipLaunchKernelGGL(klov2,    dim3(64),  dim3(256), 0, stream, ws);
  hipLaunchKernelGGL(kfinal,   dim3(1),   dim3(256), 0, stream, ws, out);
}